// Round 5
// baseline (75.586 us; speedup 1.0000x reference)
//
#include <hip/hip_runtime.h>
#include <math.h>

namespace {

constexpr int NU    = 3;    // U
constexpr int DPN   = 128;  // DP
constexpr int TOPK  = 32;   // K
constexpr int NB    = 64;   // B
constexpr int NCAND = 119;  // sum_{r=0..31} floor(32/(r+1))

// Wave-synchronous LDS fence: drain this wave's outstanding LDS ops.
// "memory" clobber orders surrounding LDS ops; sched_barrier pins scheduling
// (guide rule #18).
__device__ __forceinline__ void lds_fence() {
  asm volatile("s_waitcnt lgkmcnt(0)" ::: "memory");
  __builtin_amdgcn_sched_barrier(0);
}

// Static candidate map: c -> (r,s) with (r+1)(s+1) <= 32, r-major.
__device__ __forceinline__ void decode_rs(int c, int& r, int& s) {
  int t = c, rr = 0;
  while (true) {
    int cnt = TOPK / (rr + 1);
    if (t < cnt) break;
    t -= cnt;
    ++rr;
  }
  r = rr;
  s = t;
}

// One block (2 waves, 128 threads) per batch row.
__global__ __launch_bounds__(DPN) void kron_topk_kernel(
    const float* __restrict__ z, const float* __restrict__ log_tau,
    float* __restrict__ out) {
  const int row  = blockIdx.x;
  const int tid  = threadIdx.x;
  const int lane = tid & 63;
  const int wid  = tid >> 6;

  __shared__ __align__(16) float es[NU][DPN];  // exp(x - m)
  __shared__ __align__(16) float p[NU][DPN];   // softmax probabilities
  __shared__ float mxs[NU][2];                 // per-wave maxima
  __shared__ float sval[NU][TOPK];             // per-factor top-32 (desc)
  __shared__ int   sidx[NU][TOPK];
  __shared__ __align__(16) float cval[DPN];    // stage candidates (119 + pad)
  __shared__ __align__(16) int   cidx[DPN];
  __shared__ float aval[TOPK];                 // running stage result (desc)
  __shared__ int   aidx[TOPK];

  // ---- hoisted global loads
  const float* zr = z + row * (NU * DPN);
  float x[NU];
#pragma unroll
  for (int u = 0; u < NU; ++u) x[u] = zr[u * DPN + tid];
  const float tau = expf(log_tau[0]);
  if (tau != 1.0f) {  // uniform branch; x/1.0f == x bitwise
#pragma unroll
    for (int u = 0; u < NU; ++u) x[u] /= tau;
  }

  // ---- max: order-free fmax butterfly per wave + 2-value exchange (1 barrier)
  float mm[NU] = {x[0], x[1], x[2]};
#pragma unroll
  for (int d = 32; d > 0; d >>= 1) {
#pragma unroll
    for (int u = 0; u < NU; ++u) mm[u] = fmaxf(mm[u], __shfl_xor(mm[u], d));
  }
  if (lane == 0) {
#pragma unroll
    for (int u = 0; u < NU; ++u) mxs[u][wid] = mm[u];
  }
  __syncthreads();  // barrier 1

  float e[NU];
#pragma unroll
  for (int u = 0; u < NU; ++u) {
    float m = fmaxf(mxs[u][0], mxs[u][1]);
    e[u] = expf(x[u] - m);
    es[u][tid] = e[u];
  }
  __syncthreads();  // barrier 2

  // ---- tree-exact sum: v_j = e_j + e_{j+64}; xor butterfly 32..1; lane 0's
  // partial-sum sequence == the LDS tree (HW-verified bit-exact, absmax 0.0).
  // Both waves compute identical bits -> no broadcast barrier.
  float pv[NU];
#pragma unroll
  for (int u = 0; u < NU; ++u) {
    float v = es[u][lane] + es[u][lane + 64];
#pragma unroll
    for (int d = 32; d > 0; d >>= 1) v += __shfl_xor(v, d);
    float denom = __shfl(v, 0);
    pv[u] = e[u] / denom;
    p[u][tid] = pv[u];
  }
  __syncthreads();  // barrier 3

  // ---- per-factor exact top-32 via rank-by-count, fused over u, b128 reads
  {
    int rk[NU] = {0, 0, 0};
    const float4* p4_0 = reinterpret_cast<const float4*>(&p[0][0]);
    const float4* p4_1 = reinterpret_cast<const float4*>(&p[1][0]);
    const float4* p4_2 = reinterpret_cast<const float4*>(&p[2][0]);
#pragma unroll 8
    for (int jj = 0; jj < DPN / 4; ++jj) {
      float4 w0 = p4_0[jj];
      float4 w1 = p4_1[jj];
      float4 w2 = p4_2[jj];
      const float* w0e = &w0.x;
      const float* w1e = &w1.x;
      const float* w2e = &w2.x;
#pragma unroll
      for (int ee = 0; ee < 4; ++ee) {
        int j = 4 * jj + ee;
        rk[0] += (w0e[ee] > pv[0]) || (w0e[ee] == pv[0] && j < tid);
        rk[1] += (w1e[ee] > pv[1]) || (w1e[ee] == pv[1] && j < tid);
        rk[2] += (w2e[ee] > pv[2]) || (w2e[ee] == pv[2] && j < tid);
      }
    }
#pragma unroll
    for (int u = 0; u < NU; ++u)
      if (rk[u] < TOPK) { sval[u][rk[u]] = pv[u]; sidx[u][rk[u]] = tid; }
  }
  __syncthreads();  // barrier 4 (last block barrier)

  if (wid == 1) return;  // wave 1 done; wave 0 continues wave-synchronously

  // ---- stage chain on wave 0 alone: A := top32(p0); A := top32(A x p_u)
  if (lane < TOPK) { aval[lane] = sval[0][lane]; aidx[lane] = sidx[0][lane]; }
  lds_fence();

  int r0, s0, r1 = 0, s1 = 0;
  decode_rs(lane, r0, s0);                       // c0 = lane (< NCAND always)
  const bool has1 = (lane + 64) < NCAND;         // c1 = lane + 64
  if (has1) decode_rs(lane + 64, r1, s1);

#pragma unroll
  for (int u = 1; u < NU; ++u) {
    // build candidates: only (r+1)(s+1) <= 32 pairs can reach the top-32
    float v0 = aval[r0] * sval[u][s0];           // f32 rounding == reference
    int   i0 = aidx[r0] * DPN + sidx[u][s0];
    float v1 = -1.0f;                            // pad ranks last (probs > 0)
    int   i1 = 0x7fffffff;
    if (has1) {
      v1 = aval[r1] * sval[u][s1];
      i1 = aidx[r1] * DPN + sidx[u][s1];
    }
    cval[lane]      = v0;
    cidx[lane]      = i0;
    cval[lane + 64] = v1;
    cidx[lane + 64] = i1;
    lds_fence();  // writes (and the aval gathers) complete before rank reads

    int rk0 = 0, rk1 = 0;
    const float4* cv4 = reinterpret_cast<const float4*>(cval);
    const int4*   ci4 = reinterpret_cast<const int4*>(cidx);
#pragma unroll 8
    for (int jj = 0; jj < DPN / 4; ++jj) {
      float4 w4 = cv4[jj];
      int4   i4 = ci4[jj];
      const float* we = &w4.x;
      const int*   ie = &i4.x;
#pragma unroll
      for (int ee = 0; ee < 4; ++ee) {
        rk0 += (we[ee] > v0) || (we[ee] == v0 && ie[ee] < i0);
        rk1 += (we[ee] > v1) || (we[ee] == v1 && ie[ee] < i1);
      }
    }
    lds_fence();  // rank reads drained before aval/cval are rewritten
    if (rk0 < TOPK)         { aval[rk0] = v0; aidx[rk0] = i0; }
    if (has1 && rk1 < TOPK) { aval[rk1] = v1; aidx[rk1] = i1; }
    lds_fence();  // scatter visible before next build's aval gathers / output
  }

  // ---- write: indices chunk (as float values), then weights chunk
  if (lane < TOPK) {
    out[row * TOPK + lane]             = (float)aidx[lane];
    out[NB * TOPK + row * TOPK + lane] = aval[lane];
  }
}

}  // namespace

extern "C" void kernel_launch(void* const* d_in, const int* in_sizes, int n_in,
                              void* d_out, int out_size, void* d_ws, size_t ws_size,
                              hipStream_t stream) {
  const float* z       = (const float*)d_in[0];
  const float* log_tau = (const float*)d_in[1];
  float* out           = (float*)d_out;
  hipLaunchKernelGGL(kron_topk_kernel, dim3(NB), dim3(DPN), 0, stream,
                     z, log_tau, out);
}